// Round 1
// baseline (591.903 us; speedup 1.0000x reference)
//
#include <hip/hip_runtime.h>

namespace {
constexpr int T = 20;
constexpr int CINc = 32;
constexpr int COUTc = 64;
constexpr int HWc = 64;
constexpr int IMG = CINc * HWc * HWc;        // 131072
constexpr int OHW = 32;
constexpr int PLANE = OHW * OHW;             // 1024
constexpr int SPIKE_SZ = 8 * T * COUTc * PLANE;  // 10485760
constexpr int CNT_SZ = 8 * COUTc * PLANE;        // 524288
constexpr int CO_T = 16;                     // cout per block tile
constexpr int CCk = 8;                       // cin chunk staged in LDS
}

// Conv 3x3 pad1 + BN-fold + 2x2 maxpool.
// Spiking jobs (0..159): write pooled pre-activation into spike_out region.
// ANN jobs (160..167): BN(eval, +eps) fold + relu into ann region.
__global__ __launch_bounds__(256)
void conv_pool_kernel(const float* __restrict__ x_st,
                      const float* __restrict__ x_sc,
                      const float* __restrict__ w,
                      const float* __restrict__ b,
                      const float* __restrict__ gamma,
                      const float* __restrict__ beta,
                      const float* __restrict__ rm,
                      const float* __restrict__ rv,
                      float* __restrict__ out) {
  __shared__ float w_lds[CINc * 9 * CO_T];   // 4608 floats, layout [ci][ky][kx][co16]
  __shared__ float in_lds[CCk * 18 * 68];    // input chunk, halo'd, col 0 & 65 are pad

  const int tid = threadIdx.x;
  const int job = blockIdx.y;                // 0..167
  const bool spiking = job < 160;
  const int cog = blockIdx.x & 3;
  const int rowg = blockIdx.x >> 2;
  const int co0 = cog * CO_T;
  const int r0 = rowg * 16;                  // first pre-pool row of tile

  const float* __restrict__ xin =
      spiking ? (x_st + (size_t)job * IMG) : (x_sc + (size_t)(job - 160) * IMG);

  // Stage BN-folded weights: w_eff[co][ci][ky][kx] = w * gamma[co]/sqrt(rv (+eps))
  for (int i = tid; i < CINc * 9 * CO_T; i += 256) {
    int co_l = i & (CO_T - 1);
    int rest = i >> 4;                       // ci*9 + ky*3 + kx
    int co = co0 + co_l;
    float denom = spiking ? sqrtf(rv[co]) : sqrtf(rv[co] + 1e-5f);
    float rs = gamma[co] / denom;
    w_lds[rest * CO_T + co_l] = w[co * (CINc * 9) + rest] * rs;
  }

  const int cx = tid & 31;                   // pooled col
  const int ry = tid >> 5;                   // pooled row within tile (0..7)

  float acc[CO_T * 4];
  #pragma unroll
  for (int i = 0; i < CO_T * 4; ++i) acc[i] = 0.f;

  for (int ch = 0; ch < CINc; ch += CCk) {
    __syncthreads();
    // Stage input chunk with zero halo (rows r0-1 .. r0+16, cols -1..64 at +1 shift)
    for (int i = tid; i < CCk * 18 * 68; i += 256) {
      int col_s = i % 68;
      int rc = i / 68;
      int row_l = rc % 18;
      int ci_l = rc / 18;
      int col = col_s - 1;
      int row = r0 - 1 + row_l;
      float v = 0.f;
      if ((unsigned)col < 64u && (unsigned)row < 64u)
        v = xin[(ch + ci_l) * (HWc * HWc) + row * HWc + col];
      in_lds[i] = v;
    }
    __syncthreads();

    for (int ci = 0; ci < CCk; ++ci) {
      const float* __restrict__ ip = &in_lds[ci * (18 * 68)];
      const float* __restrict__ wp = &w_lds[(ch + ci) * 9 * CO_T];
      #pragma unroll
      for (int ky = 0; ky < 3; ++ky) {
        const int rb = (2 * ry + ky) * 68 + 2 * cx;
        float ia[4], ib[4];
        #pragma unroll
        for (int u = 0; u < 4; ++u) {
          ia[u] = ip[rb + u];
          ib[u] = ip[rb + 68 + u];
        }
        #pragma unroll
        for (int kx = 0; kx < 3; ++kx) {
          const float* __restrict__ wq = wp + (ky * 3 + kx) * CO_T;
          const float a0 = ia[kx], a1 = ia[kx + 1];
          const float b0 = ib[kx], b1 = ib[kx + 1];
          #pragma unroll
          for (int co = 0; co < CO_T; ++co) {
            float wv = wq[co];
            acc[co * 4 + 0] = fmaf(wv, a0, acc[co * 4 + 0]);
            acc[co * 4 + 1] = fmaf(wv, a1, acc[co * 4 + 1]);
            acc[co * 4 + 2] = fmaf(wv, b0, acc[co * 4 + 2]);
            acc[co * 4 + 3] = fmaf(wv, b1, acc[co * 4 + 3]);
          }
        }
      }
    }
  }

  // Epilogue: bias (uniform over pool window, so add after max) + pool + store
  const int oy = rowg * 8 + ry;
  #pragma unroll
  for (int co_l = 0; co_l < CO_T; ++co_l) {
    int co = co0 + co_l;
    float denom = spiking ? sqrtf(rv[co]) : sqrtf(rv[co] + 1e-5f);
    float rs = gamma[co] / denom;
    float beff = (b[co] - rm[co]) * rs + beta[co];
    float m = fmaxf(fmaxf(acc[co_l * 4 + 0], acc[co_l * 4 + 1]),
                    fmaxf(acc[co_l * 4 + 2], acc[co_l * 4 + 3])) + beff;
    if (spiking) {
      out[(size_t)(job * COUTc + co) * PLANE + oy * OHW + cx] = m;
    } else {
      int n = job - 160;
      out[(size_t)(SPIKE_SZ + CNT_SZ) +
          (size_t)(n * COUTc + co) * PLANE + oy * OHW + cx] = fmaxf(m, 0.f);
    }
  }
}

// In-place temporal scan over the pooled values in the spike region.
// Each neuron spikes at most once (mask is monotone): spike at first t where
// prefix-sum >= 1; count = whether it ever spiked.
__global__ __launch_bounds__(256)
void scan_kernel(float* __restrict__ out) {
  int g = blockIdx.x * 256 + threadIdx.x;    // 0 .. 524287 -> (n, c*1024+p)
  int n = g >> 16;
  int rem = g & 65535;
  size_t base = (size_t)n * (T * COUTc * PLANE) + rem;
  float pot = 0.f;
  float spiked = 0.f;
  #pragma unroll
  for (int t = 0; t < T; ++t) {
    size_t idx = base + (size_t)t * (COUTc * PLANE);
    float v = out[idx];
    pot += v;
    float s = (pot >= 1.f && spiked == 0.f) ? 1.f : 0.f;
    out[idx] = s;
    pot -= s;
    spiked = fmaxf(spiked, s);
  }
  out[(size_t)SPIKE_SZ + g] = spiked;
}

extern "C" void kernel_launch(void* const* d_in, const int* in_sizes, int n_in,
                              void* d_out, int out_size, void* d_ws, size_t ws_size,
                              hipStream_t stream) {
  const float* x_st  = (const float*)d_in[0];
  const float* x_sc  = (const float*)d_in[1];
  const float* w     = (const float*)d_in[2];
  const float* b     = (const float*)d_in[3];
  const float* gamma = (const float*)d_in[4];
  const float* beta  = (const float*)d_in[5];
  const float* rm    = (const float*)d_in[6];
  const float* rv    = (const float*)d_in[7];
  float* out = (float*)d_out;

  dim3 grid(16, 168);
  conv_pool_kernel<<<grid, 256, 0, stream>>>(x_st, x_sc, w, b, gamma, beta, rm, rv, out);
  scan_kernel<<<2048, 256, 0, stream>>>(out);
}

// Round 2
// 400.259 us; speedup vs baseline: 1.4788x; 1.4788x over previous
//
#include <hip/hip_runtime.h>

namespace {
constexpr int T = 20;
constexpr int CINc = 32;
constexpr int COUTc = 64;
constexpr int HWc = 64;
constexpr int IMG = CINc * HWc * HWc;        // 131072
constexpr int OHW = 32;
constexpr int PLANE = OHW * OHW;             // 1024
constexpr int SPIKE_SZ = 8 * T * COUTc * PLANE;  // 10485760
constexpr int CNT_SZ = 8 * COUTc * PLANE;        // 524288
constexpr int CO_T = 16;                     // cout per block tile
constexpr int CCk = 4;                       // cin chunk staged in LDS
}

// Conv 3x3 pad1 + BN-fold + 2x2 maxpool.
// Spiking jobs (0..159): write pooled pre-activation into spike_out region.
// ANN jobs (160..167): BN(eval, +eps) fold + relu into ann region.
__global__ __launch_bounds__(256, 4)
void conv_pool_kernel(const float* __restrict__ x_st,
                      const float* __restrict__ x_sc,
                      const float* __restrict__ w,
                      const float* __restrict__ b,
                      const float* __restrict__ gamma,
                      const float* __restrict__ beta,
                      const float* __restrict__ rm,
                      const float* __restrict__ rv,
                      float* __restrict__ out) {
  __shared__ float w_lds[CINc * 9 * CO_T];   // 4608 floats, layout [ci][ky][kx][co16]
  __shared__ float in_lds[CCk * 18 * 68];    // input chunk, halo'd, col 0 & 65 are pad

  const int tid = threadIdx.x;
  const int job = blockIdx.y;                // 0..167
  const bool spiking = job < 160;
  const int cog = blockIdx.x & 3;
  const int rowg = blockIdx.x >> 2;
  const int co0 = cog * CO_T;
  const int r0 = rowg * 16;                  // first pre-pool row of tile

  const float* __restrict__ xin =
      spiking ? (x_st + (size_t)job * IMG) : (x_sc + (size_t)(job - 160) * IMG);

  // Stage BN-folded weights: w_eff[co][ci][ky][kx] = w * gamma[co]/sqrt(rv (+eps))
  for (int i = tid; i < CINc * 9 * CO_T; i += 256) {
    int co_l = i & (CO_T - 1);
    int rest = i >> 4;                       // ci*9 + ky*3 + kx
    int co = co0 + co_l;
    float denom = spiking ? sqrtf(rv[co]) : sqrtf(rv[co] + 1e-5f);
    float rs = gamma[co] / denom;
    w_lds[rest * CO_T + co_l] = w[co * (CINc * 9) + rest] * rs;
  }

  const int cx = tid & 31;                   // pooled col
  const int ry = tid >> 5;                   // pooled row within tile (0..7)

  float acc[CO_T * 4];
  #pragma unroll
  for (int i = 0; i < CO_T * 4; ++i) acc[i] = 0.f;

  for (int ch = 0; ch < CINc; ch += CCk) {
    __syncthreads();
    // Stage input chunk with zero halo (rows r0-1 .. r0+16, cols -1..64 at +1 shift)
    for (int i = tid; i < CCk * 18 * 68; i += 256) {
      int col_s = i % 68;
      int rc = i / 68;
      int row_l = rc % 18;
      int ci_l = rc / 18;
      int col = col_s - 1;
      int row = r0 - 1 + row_l;
      float v = 0.f;
      if ((unsigned)col < 64u && (unsigned)row < 64u)
        v = xin[(ch + ci_l) * (HWc * HWc) + row * HWc + col];
      in_lds[i] = v;
    }
    __syncthreads();

    for (int ci = 0; ci < CCk; ++ci) {
      const float* __restrict__ ip = &in_lds[ci * (18 * 68)];
      const float* __restrict__ wp = &w_lds[(ch + ci) * 9 * CO_T];
      #pragma unroll
      for (int ky = 0; ky < 3; ++ky) {
        const int rb = (2 * ry + ky) * 68 + 2 * cx;   // even -> float2-aligned
        float ia[4], ib[4];
        {
          const float2 a01 = *reinterpret_cast<const float2*>(ip + rb);
          const float2 a23 = *reinterpret_cast<const float2*>(ip + rb + 2);
          const float2 b01 = *reinterpret_cast<const float2*>(ip + rb + 68);
          const float2 b23 = *reinterpret_cast<const float2*>(ip + rb + 70);
          ia[0] = a01.x; ia[1] = a01.y; ia[2] = a23.x; ia[3] = a23.y;
          ib[0] = b01.x; ib[1] = b01.y; ib[2] = b23.x; ib[3] = b23.y;
        }
        #pragma unroll
        for (int kx = 0; kx < 3; ++kx) {
          const float4* __restrict__ wq4 =
              reinterpret_cast<const float4*>(wp + (ky * 3 + kx) * CO_T);
          const float a0 = ia[kx], a1 = ia[kx + 1];
          const float b0 = ib[kx], b1 = ib[kx + 1];
          #pragma unroll
          for (int q = 0; q < 4; ++q) {
            const float4 wv = wq4[q];
            float* ac = acc + (q * 4) * 4;
            ac[0]  = fmaf(wv.x, a0, ac[0]);
            ac[1]  = fmaf(wv.x, a1, ac[1]);
            ac[2]  = fmaf(wv.x, b0, ac[2]);
            ac[3]  = fmaf(wv.x, b1, ac[3]);
            ac[4]  = fmaf(wv.y, a0, ac[4]);
            ac[5]  = fmaf(wv.y, a1, ac[5]);
            ac[6]  = fmaf(wv.y, b0, ac[6]);
            ac[7]  = fmaf(wv.y, b1, ac[7]);
            ac[8]  = fmaf(wv.z, a0, ac[8]);
            ac[9]  = fmaf(wv.z, a1, ac[9]);
            ac[10] = fmaf(wv.z, b0, ac[10]);
            ac[11] = fmaf(wv.z, b1, ac[11]);
            ac[12] = fmaf(wv.w, a0, ac[12]);
            ac[13] = fmaf(wv.w, a1, ac[13]);
            ac[14] = fmaf(wv.w, b0, ac[14]);
            ac[15] = fmaf(wv.w, b1, ac[15]);
          }
        }
      }
    }
  }

  // Epilogue: bias (uniform over pool window, so add after max) + pool + store
  const int oy = rowg * 8 + ry;
  #pragma unroll
  for (int co_l = 0; co_l < CO_T; ++co_l) {
    int co = co0 + co_l;
    float denom = spiking ? sqrtf(rv[co]) : sqrtf(rv[co] + 1e-5f);
    float rs = gamma[co] / denom;
    float beff = (b[co] - rm[co]) * rs + beta[co];
    float m = fmaxf(fmaxf(acc[co_l * 4 + 0], acc[co_l * 4 + 1]),
                    fmaxf(acc[co_l * 4 + 2], acc[co_l * 4 + 3])) + beff;
    if (spiking) {
      out[(size_t)(job * COUTc + co) * PLANE + oy * OHW + cx] = m;
    } else {
      int n = job - 160;
      out[(size_t)(SPIKE_SZ + CNT_SZ) +
          (size_t)(n * COUTc + co) * PLANE + oy * OHW + cx] = fmaxf(m, 0.f);
    }
  }
}

// In-place temporal scan over the pooled values in the spike region.
// Each neuron spikes at most once (mask is monotone): spike at first t where
// prefix-sum >= 1; count = whether it ever spiked.
__global__ __launch_bounds__(256)
void scan_kernel(float* __restrict__ out) {
  int g = blockIdx.x * 256 + threadIdx.x;    // 0 .. 524287 -> (n, c*1024+p)
  int n = g >> 16;
  int rem = g & 65535;
  size_t base = (size_t)n * (T * COUTc * PLANE) + rem;
  float pot = 0.f;
  float spiked = 0.f;
  #pragma unroll
  for (int t = 0; t < T; ++t) {
    size_t idx = base + (size_t)t * (COUTc * PLANE);
    float v = out[idx];
    pot += v;
    float s = (pot >= 1.f && spiked == 0.f) ? 1.f : 0.f;
    out[idx] = s;
    pot -= s;
    spiked = fmaxf(spiked, s);
  }
  out[(size_t)SPIKE_SZ + g] = spiked;
}

extern "C" void kernel_launch(void* const* d_in, const int* in_sizes, int n_in,
                              void* d_out, int out_size, void* d_ws, size_t ws_size,
                              hipStream_t stream) {
  const float* x_st  = (const float*)d_in[0];
  const float* x_sc  = (const float*)d_in[1];
  const float* w     = (const float*)d_in[2];
  const float* b     = (const float*)d_in[3];
  const float* gamma = (const float*)d_in[4];
  const float* beta  = (const float*)d_in[5];
  const float* rm    = (const float*)d_in[6];
  const float* rv    = (const float*)d_in[7];
  float* out = (float*)d_out;

  dim3 grid(16, 168);
  conv_pool_kernel<<<grid, 256, 0, stream>>>(x_st, x_sc, w, b, gamma, beta, rm, rv, out);
  scan_kernel<<<2048, 256, 0, stream>>>(out);
}

// Round 4
// 100.938 us; speedup vs baseline: 5.8640x; 3.9654x over previous
//
#include <hip/hip_runtime.h>

namespace {
constexpr int T = 20;
constexpr int CINc = 32;
constexpr int COUTc = 64;
constexpr int HWc = 64;
constexpr int IMG = CINc * HWc * HWc;            // 131072
constexpr int OHW = 32;
constexpr int PLANE = OHW * OHW;                 // 1024
constexpr int SPIKE_SZ = 8 * T * COUTc * PLANE;  // 10485760
constexpr int CNT_SZ = 8 * COUTc * PLANE;        // 524288
constexpr int W_ELEMS = 9 * COUTc * CINc;        // 18432 per (set, hi/lo)
constexpr float LO_SCALE = 16777216.0f;          // 2^24
constexpr float LO_INV = 5.9604644775390625e-8f; // 2^-24
}

typedef _Float16 half8 __attribute__((ext_vector_type(8)));
typedef float f32x4 __attribute__((ext_vector_type(4)));

__device__ __forceinline__ unsigned short h_bits(_Float16 h) {
  return __builtin_bit_cast(unsigned short, h);
}

// Precompute BN-folded weights in MFMA B-fragment layout, fp16 split:
// w = H + L*2^-24 (L = fp16((w-H)*2^24)).
// ws ushort layout: [set(spike=0,ann=1)][hi=0,lo=1][tap][cout][cin]
__global__ void wprep_kernel(const float* __restrict__ w,
                             const float* __restrict__ gamma,
                             const float* __restrict__ rv,
                             unsigned short* __restrict__ ws) {
  int idx = blockIdx.x * 256 + threadIdx.x;
  if (idx >= 2 * W_ELEMS) return;
  int ci = idx & 31;
  int co = (idx >> 5) & 63;
  int v = idx >> 11;            // 0..17
  int tap = v % 9;
  int set = v / 9;
  float denom = set ? sqrtf(rv[co] + 1e-5f) : sqrtf(rv[co]);
  float val = w[(co * 32 + ci) * 9 + tap] * (gamma[co] / denom);
  _Float16 h = (_Float16)val;
  _Float16 l = (_Float16)((val - (float)h) * LO_SCALE);
  int base = set * (2 * W_ELEMS) + (tap * 64 + co) * 32 + ci;
  ws[base] = h_bits(h);
  ws[base + W_ELEMS] = h_bits(l);
}

// Conv 3x3 pad1 (implicit GEMM via fp16-split MFMA) + BN-fold + 2x2 maxpool.
// Block: 4 conv rows x 64 cols x 64 couts. 4 waves: wave = 2 conv rows x 32 couts.
__global__ __launch_bounds__(256, 2)
void conv_mfma_kernel(const float* __restrict__ x_st,
                      const float* __restrict__ x_sc,
                      const float* __restrict__ b,
                      const float* __restrict__ gamma,
                      const float* __restrict__ beta,
                      const float* __restrict__ rm,
                      const float* __restrict__ rv,
                      const unsigned short* __restrict__ ws,
                      float* __restrict__ out) {
  // NHWC fp16 tiles: [6 rows][66 col-slots (slot0/65 = zero pad)][32 ci]
  __shared__ unsigned short in_h[6 * 66 * 32];
  __shared__ unsigned short in_l[6 * 66 * 32];

  const int tid = threadIdx.x;
  const int band = blockIdx.x;           // 0..15 -> conv rows 4*band..+3
  const int job = blockIdx.y;            // 0..167
  const bool spiking = job < 160;
  const int r0 = band * 4;

  const float* __restrict__ xin =
      spiking ? (x_st + (size_t)job * IMG) : (x_sc + (size_t)(job - 160) * IMG);

  // ---- Stage: planar fp32 -> NHWC fp16 hi + scaled-lo in LDS ----
  {
    const int col = tid & 63;
    const int g = tid >> 6;              // ci group of 8
    for (int r6 = 0; r6 < 6; ++r6) {
      int row = r0 - 1 + r6;
      float vv[8];
      if ((unsigned)row < 64u) {
        const float* src = xin + (g * 8) * (HWc * HWc) + row * HWc + col;
        #pragma unroll
        for (int jj = 0; jj < 8; ++jj) vv[jj] = src[jj * (HWc * HWc)];
      } else {
        #pragma unroll
        for (int jj = 0; jj < 8; ++jj) vv[jj] = 0.f;
      }
      unsigned int hw[4], lw[4];
      #pragma unroll
      for (int q = 0; q < 4; ++q) {
        float x0 = vv[2 * q], x1 = vv[2 * q + 1];
        _Float16 h0 = (_Float16)x0;
        _Float16 h1 = (_Float16)x1;
        _Float16 l0 = (_Float16)((x0 - (float)h0) * LO_SCALE);
        _Float16 l1 = (_Float16)((x1 - (float)h1) * LO_SCALE);
        hw[q] = (unsigned int)h_bits(h0) | ((unsigned int)h_bits(h1) << 16);
        lw[q] = (unsigned int)h_bits(l0) | ((unsigned int)h_bits(l1) << 16);
      }
      int base = (r6 * 66 + col + 1) * 32 + g * 8;   // ushort index, %8==0
      *reinterpret_cast<uint4*>(&in_h[base]) = make_uint4(hw[0], hw[1], hw[2], hw[3]);
      *reinterpret_cast<uint4*>(&in_l[base]) = make_uint4(lw[0], lw[1], lw[2], lw[3]);
    }
    // zero the pad col-slots 0 and 65
    if (tid < 12) {
      int r6 = tid >> 1;
      int slot = (tid & 1) * 65;
      int base = (r6 * 66 + slot) * 32;
      uint4 z = make_uint4(0, 0, 0, 0);
      #pragma unroll
      for (int q = 0; q < 4; ++q) {
        *reinterpret_cast<uint4*>(&in_h[base + q * 8]) = z;
        *reinterpret_cast<uint4*>(&in_l[base + q * 8]) = z;
      }
    }
  }
  __syncthreads();

  // ---- MFMA main loop ----
  const int lane = tid & 63;
  const int wv = tid >> 6;
  const int p = wv & 1;                  // conv-row pair -> pooled row
  const int co0 = (wv >> 1) * 32;        // cout half
  const int laneoff = (lane & 15) * 64 + (lane >> 4) * 16;   // bytes

  const char* Hbase = (const char*)in_h;
  const char* Lbase = (const char*)in_l;
  const char* WS = (const char*)ws + (spiking ? 0 : 4 * W_ELEMS);  // bytes
  const int WLO = 2 * W_ELEMS;           // byte offset hi->lo

  f32x4 accH[8][2];                      // scale-1 accumulator (h*H)
  f32x4 accL[8][2];                      // scale-2^24 accumulator (h*L' + l'*H)
  #pragma unroll
  for (int m = 0; m < 8; ++m) {
    accH[m][0] = (f32x4)(0.f);
    accH[m][1] = (f32x4)(0.f);
    accL[m][0] = (f32x4)(0.f);
    accL[m][1] = (f32x4)(0.f);
  }

  #pragma unroll
  for (int ky = 0; ky < 3; ++ky) {
    #pragma unroll
    for (int kx = 0; kx < 3; ++kx) {
      const int tap = ky * 3 + kx;
      const char* wp = WS + (tap * 64 + co0) * 64 + laneoff;
      half8 bh0 = *reinterpret_cast<const half8*>(wp);
      half8 bh1 = *reinterpret_cast<const half8*>(wp + 16 * 64);
      half8 bl0 = *reinterpret_cast<const half8*>(wp + WLO);
      half8 bl1 = *reinterpret_cast<const half8*>(wp + WLO + 16 * 64);
      #pragma unroll
      for (int m = 0; m < 8; ++m) {
        const int rl = 2 * p + (m >> 2) + ky;          // 0..5
        const int boff = (rl * 66 + (m & 3) * 16 + kx) * 64;
        half8 ah = *reinterpret_cast<const half8*>(Hbase + boff + laneoff);
        half8 al = *reinterpret_cast<const half8*>(Lbase + boff + laneoff);
        accH[m][0] = __builtin_amdgcn_mfma_f32_16x16x32_f16(ah, bh0, accH[m][0], 0, 0, 0);
        accH[m][1] = __builtin_amdgcn_mfma_f32_16x16x32_f16(ah, bh1, accH[m][1], 0, 0, 0);
        accL[m][0] = __builtin_amdgcn_mfma_f32_16x16x32_f16(al, bh0, accL[m][0], 0, 0, 0);
        accL[m][0] = __builtin_amdgcn_mfma_f32_16x16x32_f16(ah, bl0, accL[m][0], 0, 0, 0);
        accL[m][1] = __builtin_amdgcn_mfma_f32_16x16x32_f16(al, bh1, accL[m][1], 0, 0, 0);
        accL[m][1] = __builtin_amdgcn_mfma_f32_16x16x32_f16(ah, bl1, accL[m][1], 0, 0, 0);
      }
    }
  }

  // ---- Epilogue: combine scales, 2x2 maxpool, bias ----
  const int oy = band * 2 + p;
  #pragma unroll
  for (int j = 0; j < 2; ++j) {
    int co = co0 + j * 16 + (lane & 15);
    float denom = spiking ? sqrtf(rv[co]) : sqrtf(rv[co] + 1e-5f);
    float rs = gamma[co] / denom;
    float beff = (b[co] - rm[co]) * rs + beta[co];
    #pragma unroll
    for (int m = 0; m < 4; ++m) {
      f32x4 tH = accH[m][j], tL = accL[m][j];
      f32x4 bH = accH[m + 4][j], bL = accL[m + 4][j];
      float t0 = fmaf(LO_INV, tL[0], tH[0]);
      float t1 = fmaf(LO_INV, tL[1], tH[1]);
      float t2 = fmaf(LO_INV, tL[2], tH[2]);
      float t3 = fmaf(LO_INV, tL[3], tH[3]);
      float b0 = fmaf(LO_INV, bL[0], bH[0]);
      float b1 = fmaf(LO_INV, bL[1], bH[1]);
      float b2 = fmaf(LO_INV, bL[2], bH[2]);
      float b3 = fmaf(LO_INV, bL[3], bH[3]);
      float v0 = fmaxf(fmaxf(t0, t1), fmaxf(b0, b1)) + beff;
      float v1 = fmaxf(fmaxf(t2, t3), fmaxf(b2, b3)) + beff;
      int ox = m * 8 + (lane >> 4) * 2;
      if (spiking) {
        float2* dst = reinterpret_cast<float2*>(
            out + (size_t)(job * COUTc + co) * PLANE + oy * OHW + ox);
        *dst = make_float2(v0, v1);
      } else {
        int n = job - 160;
        float2* dst = reinterpret_cast<float2*>(
            out + (size_t)(SPIKE_SZ + CNT_SZ) +
            (size_t)(n * COUTc + co) * PLANE + oy * OHW + ox);
        *dst = make_float2(fmaxf(v0, 0.f), fmaxf(v1, 0.f));
      }
    }
  }
}

// In-place temporal scan: each neuron spikes at most once (mask latches).
__global__ __launch_bounds__(256)
void scan_kernel(float* __restrict__ out) {
  int g = blockIdx.x * 256 + threadIdx.x;    // 0 .. 524287
  int n = g >> 16;
  int rem = g & 65535;
  size_t base = (size_t)n * (T * COUTc * PLANE) + rem;
  float pot = 0.f;
  float spiked = 0.f;
  #pragma unroll
  for (int t = 0; t < T; ++t) {
    size_t idx = base + (size_t)t * (COUTc * PLANE);
    float v = out[idx];
    pot += v;
    float s = (pot >= 1.f && spiked == 0.f) ? 1.f : 0.f;
    out[idx] = s;
    pot -= s;
    spiked = fmaxf(spiked, s);
  }
  out[(size_t)SPIKE_SZ + g] = spiked;
}

extern "C" void kernel_launch(void* const* d_in, const int* in_sizes, int n_in,
                              void* d_out, int out_size, void* d_ws, size_t ws_size,
                              hipStream_t stream) {
  const float* x_st  = (const float*)d_in[0];
  const float* x_sc  = (const float*)d_in[1];
  const float* w     = (const float*)d_in[2];
  const float* b     = (const float*)d_in[3];
  const float* gamma = (const float*)d_in[4];
  const float* beta  = (const float*)d_in[5];
  const float* rm    = (const float*)d_in[6];
  const float* rv    = (const float*)d_in[7];
  float* out = (float*)d_out;
  unsigned short* wsu = (unsigned short*)d_ws;

  wprep_kernel<<<(2 * W_ELEMS + 255) / 256, 256, 0, stream>>>(w, gamma, rv, wsu);
  dim3 grid(16, 168);
  conv_mfma_kernel<<<grid, 256, 0, stream>>>(x_st, x_sc, b, gamma, beta, rm, rv, wsu, out);
  scan_kernel<<<2048, 256, 0, stream>>>(out);
}